// Round 1
// baseline (631.160 us; speedup 1.0000x reference)
//
#include <hip/hip_runtime.h>

// NsoltBlockIdct2dLayer: 3 x (32,128,128,64) f32 -> (32,3,1024,1024) f32
// Per 64-coef block: quadrant unpack (ee,oo,oe,eo) -> 8x8 V, Y = C^T V C,
// flat write of the 64 results contiguously.
//
// Layout facts (derived from the reference's flat reshape):
//   in  block b (b = ((s*128+r)*128+c)): coefs at in[b*64 .. b*64+63]
//   out block b: out[s*3*1048576 + ch*1048576 + (b&16383)*64 + m*8 + n]
// So both input and output of a block are 64 contiguous floats.

#define STRIDE4 17  // 68 floats per block in LDS (+4 pad: breaks bank aliasing)

constexpr float K0 = 0.35355339059327373f;  // 1/sqrt(8)
constexpr float C1 = 0.49039264020161522f;  // 0.5*cos(1*pi/16)
constexpr float C2 = 0.46193976625564337f;  // 0.5*cos(2*pi/16)
constexpr float C3 = 0.41573480615127262f;  // 0.5*cos(3*pi/16)
constexpr float C4 = 0.35355339059327379f;  // 0.5*cos(4*pi/16)
constexpr float C5 = 0.27778511650980114f;  // 0.5*cos(5*pi/16)
constexpr float C6 = 0.19134171618254492f;  // 0.5*cos(6*pi/16)
constexpr float C7 = 0.09754516100806413f;  // 0.5*cos(7*pi/16)

// y[n] = sum_l t[l] * C[l][n], 8-pt orthonormal IDCT of one row, even/odd split
__device__ __forceinline__ void idct8_row(const float t[8], float y[8]) {
    float e0 = K0*t[0] + C2*t[2] + C4*t[4] + C6*t[6];
    float e1 = K0*t[0] + C6*t[2] - C4*t[4] - C2*t[6];
    float e2 = K0*t[0] - C6*t[2] - C4*t[4] + C2*t[6];
    float e3 = K0*t[0] - C2*t[2] + C4*t[4] - C6*t[6];
    float o0 = C1*t[1] + C3*t[3] + C5*t[5] + C7*t[7];
    float o1 = C3*t[1] - C7*t[3] - C1*t[5] - C5*t[7];
    float o2 = C5*t[1] - C1*t[3] + C7*t[5] + C3*t[7];
    float o3 = C7*t[1] - C5*t[3] + C3*t[5] - C1*t[7];
    y[0] = e0 + o0; y[7] = e0 - o0;
    y[1] = e1 + o1; y[6] = e1 - o1;
    y[2] = e2 + o2; y[5] = e2 - o2;
    y[3] = e3 + o3; y[4] = e3 - o3;
}

__global__ __launch_bounds__(64) void nsolt_idct_kernel(
        const float* __restrict__ x0, const float* __restrict__ x1,
        const float* __restrict__ x2, float* __restrict__ out) {
    __shared__ float4 lds4[64 * STRIDE4];  // 17.4 KB
    const unsigned tid = threadIdx.x;
    const unsigned wg  = blockIdx.x;
    const unsigned ch  = wg >> 13;          // input/channel 0..2 (8192 wgs each)
    const unsigned g   = wg & 8191u;        // group within input
    const float* in = (ch == 0) ? x0 : ((ch == 1) ? x1 : x2);
    const unsigned b0 = g << 6;             // first block index (64 blocks/wg)
    const unsigned s  = g >> 8;             // sample (256 groups per sample)
    const unsigned out_base = s * 3145728u + ch * 1048576u + ((g & 255u) << 12);

    // ---- Phase A: coalesced global -> LDS (padded stride-68 layout) ----
    const float4* in4 = (const float4*)(in + (size_t)b0 * 64u);
    float4 r[16];
#pragma unroll
    for (int i = 0; i < 16; ++i) r[i] = in4[i * 64 + (int)tid];
#pragma unroll
    for (int i = 0; i < 16; ++i) {
        int f = i * 64 + (int)tid;
        lds4[(f >> 4) * STRIDE4 + (f & 15)] = r[i];
    }
    __syncthreads();

    // ---- Phase B: stage-1 column transform T[m][l] = sum_k C[k][m] V[k][l]
    // with even/odd-k butterfly; V rows read straight from quadrant packing:
    //   even k=2i: even cols = cee (f4 idx i),   odd cols = ceo (12+i)
    //   odd  k=2i+1: even cols = coe (8+i),      odd cols = coo (4+i)
    const int base4 = (int)tid * STRIDE4;
    float te[4][8], to[4][8];
#pragma unroll
    for (int m = 0; m < 4; ++m)
#pragma unroll
        for (int l = 0; l < 8; ++l) { te[m][l] = 0.f; to[m][l] = 0.f; }

    constexpr float CE[4][4] = {{K0, K0, K0, K0},
                                {C2, C6, -C6, -C2},
                                {C4, -C4, -C4, C4},
                                {C6, -C2, C2, -C6}};
    constexpr float CO[4][4] = {{C1, C3, C5, C7},
                                {C3, -C7, -C1, -C5},
                                {C5, -C1, C7, C3},
                                {C7, -C5, C3, -C1}};

#pragma unroll
    for (int kk = 0; kk < 4; ++kk) {
        float4 ve = lds4[base4 + kk];        // V[2kk][0,2,4,6]
        float4 vo = lds4[base4 + 12 + kk];   // V[2kk][1,3,5,7]
        float4 ue = lds4[base4 + 8 + kk];    // V[2kk+1][0,2,4,6]
        float4 uo = lds4[base4 + 4 + kk];    // V[2kk+1][1,3,5,7]
#pragma unroll
        for (int m = 0; m < 4; ++m) {
            float w = CE[kk][m];
            te[m][0] += w * ve.x; te[m][2] += w * ve.y;
            te[m][4] += w * ve.z; te[m][6] += w * ve.w;
            te[m][1] += w * vo.x; te[m][3] += w * vo.y;
            te[m][5] += w * vo.z; te[m][7] += w * vo.w;
            float u = CO[kk][m];
            to[m][0] += u * ue.x; to[m][2] += u * ue.y;
            to[m][4] += u * ue.z; to[m][6] += u * ue.w;
            to[m][1] += u * uo.x; to[m][3] += u * uo.y;
            to[m][5] += u * uo.z; to[m][7] += u * uo.w;
        }
    }

    // ---- Phase C: stage-2 row transforms; write rows back to own LDS slot
    // (no barrier needed: each thread reads/writes only its own block region)
#pragma unroll
    for (int m = 0; m < 4; ++m) {
        float tt[8], tb[8], y[8];
#pragma unroll
        for (int l = 0; l < 8; ++l) {
            tt[l] = te[m][l] + to[m][l];   // row m
            tb[l] = te[m][l] - to[m][l];   // row 7-m
        }
        idct8_row(tt, y);
        lds4[base4 + 2 * m]     = make_float4(y[0], y[1], y[2], y[3]);
        lds4[base4 + 2 * m + 1] = make_float4(y[4], y[5], y[6], y[7]);
        idct8_row(tb, y);
        lds4[base4 + 2 * (7 - m)]     = make_float4(y[0], y[1], y[2], y[3]);
        lds4[base4 + 2 * (7 - m) + 1] = make_float4(y[4], y[5], y[6], y[7]);
    }
    __syncthreads();

    // ---- Phase D: coalesced LDS -> global ----
    float4* out4 = (float4*)(out + out_base);
#pragma unroll
    for (int i = 0; i < 16; ++i) {
        int f = i * 64 + (int)tid;
        out4[f] = lds4[(f >> 4) * STRIDE4 + (f & 15)];
    }
}

extern "C" void kernel_launch(void* const* d_in, const int* in_sizes, int n_in,
                              void* d_out, int out_size, void* d_ws, size_t ws_size,
                              hipStream_t stream) {
    const float* x0 = (const float*)d_in[0];
    const float* x1 = (const float*)d_in[1];
    const float* x2 = (const float*)d_in[2];
    float* out = (float*)d_out;
    // 3 inputs * 524288 blocks / 64 blocks-per-wg = 24576 workgroups
    nsolt_idct_kernel<<<dim3(24576), dim3(64), 0, stream>>>(x0, x1, x2, out);
}